// Round 11
// baseline (2661.662 us; speedup 1.0000x reference)
//
#include <hip/hip_runtime.h>
#include <stdint.h>

typedef unsigned short u16;
typedef unsigned long long u64;
typedef __attribute__((ext_vector_type(8))) short short8;
typedef __attribute__((ext_vector_type(4))) float f32x4;

// ---------------- device-global blob ----------------
#define SZ_BIGW    (4096ull*1024ull*2ull)          // [4096x1024] bf16, fragment-tiled
#define OFF_WHH1   (0ull)
#define OFF_WIH2   (OFF_WHH1 + SZ_BIGW)
#define OFF_WHH2   (OFF_WIH2 + SZ_BIGW)
#define OFF_WIH3   (OFF_WHH2 + SZ_BIGW)
#define OFF_WHH3   (OFF_WIH3 + SZ_BIGW)
#define OFF_MCOMB  (OFF_WHH3 + SZ_BIGW)            // W_ih1 @ W_dec  [4096x1024]
#define OFF_WIH1   (OFF_MCOMB + SZ_BIGW)           // [4096 x 160(pad of 132)]
#define SZ_WIH1    (4096ull*160ull*2ull)
#define OFF_WDECF  (OFF_WIH1 + SZ_WIH1)            // W_dec as B-op, rows f(pad160) x K=1024
#define SZ_WDECF   (160ull*1024ull*2ull)
#define OFF_WDECB  (OFF_WDECF + SZ_WDECF)          // W_dec^T as B-op, rows k(1024) x f(pad160)
#define SZ_WDECB   (1024ull*160ull*2ull)
#define OFF_XPRIM  (OFF_WDECB + SZ_WDECB)          // [64 t][20 kc][32 b][8] bf16
#define SZ_XPRIM   (64ull*5120ull*2ull)
#define OFF_H2HIST (OFF_XPRIM + SZ_XPRIM)          // 129 slots (A-layout), slot0 = prime t=63
#define SZ_HSLOT   (32768ull*2ull)                 // 64 KB per h slot
#define SZ_H2HIST  (129ull*SZ_HSLOT)
#define OFF_H0R    (OFF_H2HIST + SZ_H2HIST)        // write-once ring, depth 192
#define SZ_HR      (192ull*SZ_HSLOT)
#define OFF_H1R    (OFF_H0R + SZ_HR)
#define OFF_H2R    (OFF_H1R + SZ_HR)               // prime-phase ring, depth 64
#define SZ_H2R     (64ull*SZ_HSLOT)
#define OFF_ZEROH  (OFF_H2R + SZ_H2R)              // one zero h slot
#define OFF_FLAGS  (OFF_ZEROH + SZ_HSLOT)          // 4 x 256 u32 flags (FP,F1,F2,F3)
#define SZ_FLAGS   (4096ull)
#define OFF_BS1    (OFF_FLAGS + SZ_FLAGS)          // bias sums fp32 [4096] x4
#define OFF_BS1G   (OFF_BS1 + 16384ull)
#define OFF_BS2    (OFF_BS1G + 16384ull)
#define OFF_BS3    (OFF_BS2 + 16384ull)
#define BLOB_SIZE  (OFF_BS3 + 16384ull)

__device__ unsigned char g_blob[BLOB_SIZE];

// zero region: ZEROH + FLAGS, contiguous
#define ZERO_BYTES (SZ_HSLOT + SZ_FLAGS)

__device__ __forceinline__ u16 f2bf(float f) {
  unsigned u = __float_as_uint(f);
  u += 0x7fffu + ((u >> 16) & 1u);
  return (u16)(u >> 16);
}
__device__ __forceinline__ float sigm(float x) { return 1.f / (1.f + __expf(-x)); }
__device__ __forceinline__ float tanh_(float x) {
  x = fminf(fmaxf(x, -40.f), 40.f);
  float e = __expf(2.f * x);
  return (e - 1.f) / (e + 1.f);
}

// ---------------- fused prep kernels (unchanged) ----------------
__device__ __forceinline__ void dev_swizzle(const float* __restrict__ src, u16* __restrict__ dst,
                                            int J, int Jsrc, int Kpad, int Ksrc, int srcld,
                                            int transposed, int perm, int bbase, int nblocks) {
  int total = J * Kpad;
  int nkc = Kpad >> 3;
  for (int o = (blockIdx.x - bbase) * 256 + threadIdx.x; o < total; o += nblocks * 256) {
    int chunk = o >> 7, within = o & 127;
    int nt = chunk / nkc, kc = chunk - nt * nkc;
    int jr = within >> 3, ke = within & 7;
    int j = perm ? ((jr >> 2) * 1024 + nt * 4 + (jr & 3)) : (nt * 16 + jr);
    int k = kc * 8 + ke;
    float v = 0.f;
    if (j < Jsrc && k < Ksrc)
      v = transposed ? src[(size_t)k * srcld + j] : src[(size_t)j * srcld + k];
    dst[o] = f2bf(v);
  }
}

__global__ __launch_bounds__(256) void k_prep1(const float* __restrict__ s0, const float* __restrict__ s1,
                                               const float* __restrict__ s2, const float* __restrict__ s3,
                                               const float* __restrict__ s4, unsigned char* blob) {
  int m = blockIdx.x >> 9;
  const float* src = (m == 0) ? s0 : (m == 1) ? s1 : (m == 2) ? s2 : (m == 3) ? s3 : s4;
  u16* dst = (u16*)(blob + (size_t)m * SZ_BIGW);
  int nkc = 128;   // Kpad=1024
  for (int o = (blockIdx.x & 511) * 256 + threadIdx.x; o < 4096 * 1024; o += 512 * 256) {
    int chunk = o >> 7, within = o & 127;
    int nt = chunk / nkc, kc = chunk - nt * nkc;
    int jr = within >> 3, ke = within & 7;
    int j = (jr >> 2) * 1024 + nt * 4 + (jr & 3);
    int k = kc * 8 + ke;
    dst[o] = f2bf(src[(size_t)j * 1024 + k]);
  }
}

__global__ __launch_bounds__(256) void k_prep2(const float* __restrict__ Wih1, const float* __restrict__ Wdec,
                                               const float* __restrict__ iseq,
                                               const float* bih1, const float* bhh1,
                                               const float* bih2, const float* bhh2,
                                               const float* bih3, const float* bhh3,
                                               const float* __restrict__ bdec, unsigned char* blob) {
  int bid = blockIdx.x;
  if (bid < 64) {
    uint4* p = (uint4*)(blob + OFF_ZEROH);
    int i = bid * 256 + threadIdx.x;
    if (i < (int)(ZERO_BYTES / 16)) p[i] = make_uint4(0u, 0u, 0u, 0u);
  } else if (bid < 320) {
    dev_swizzle(Wih1, (u16*)(blob + OFF_WIH1), 4096, 4096, 160, 132, 132, 0, 1, 64, 256);
  } else if (bid < 352) {
    dev_swizzle(Wdec, (u16*)(blob + OFF_WDECF), 160, 132, 1024, 1024, 1024, 0, 0, 320, 32);
  } else if (bid < 384) {
    dev_swizzle(Wdec, (u16*)(blob + OFF_WDECB), 1024, 1024, 160, 132, 1024, 1, 0, 352, 32);
  } else if (bid < 480) {
    u16* dst = (u16*)(blob + OFF_XPRIM);
    for (int o = (bid - 384) * 256 + threadIdx.x; o < 64 * 5120; o += 96 * 256) {
      int t = o / 5120, rem = o - t * 5120;
      int kc = rem >> 8, b = (rem >> 3) & 31, ke = rem & 7;
      int k = kc * 8 + ke;
      float v = (k < 132) ? iseq[(size_t)b * (64 * 132) + t * 132 + k] : 0.f;
      dst[o] = f2bf(v);
    }
  } else {
    int j = (bid - 480) * 256 + threadIdx.x;
    if (j < 4096) {
      float* bs1 = (float*)(blob + OFF_BS1);
      float* bs1g = (float*)(blob + OFF_BS1G);
      float* bs2 = (float*)(blob + OFF_BS2);
      float* bs3 = (float*)(blob + OFF_BS3);
      float s1 = bih1[j] + bhh1[j];
      float bc = 0.f;
      const float* wr = Wih1 + (size_t)j * 132;
      for (int f = 0; f < 132; ++f) bc += wr[f] * bdec[f];
      bs1[j] = s1;
      bs1g[j] = s1 + bc;
      bs2[j] = bih2[j] + bhh2[j];
      bs3[j] = bih3[j] + bhh3[j];
    }
  }
}

// Mcomb[j][k] = sum_f Wih1[j][f]*Wdec[f][k]; A-rows and C-rows permute identically.
__global__ __launch_bounds__(256) void k_mcomb(const u16* __restrict__ A, const u16* __restrict__ Bm,
                                               u16* __restrict__ dst) {
  int blk = blockIdx.x;                   // 4096 = 256 mt x 16 jg
  int mt = blk & 255, jg = blk >> 8;
  int w = threadIdx.x >> 6, l = threadIdx.x & 63, q = l >> 4, r = l & 15;
  int nt = jg * 4 + w;
  f32x4 acc = {};
  for (int ks = 0; ks < 5; ++ks) {
    short8 a = *(const short8*)(A + ((size_t)mt * 20 + ks * 4 + q) * 128 + r * 8);
    short8 b = *(const short8*)(Bm + ((size_t)nt * 20 + ks * 4 + q) * 128 + r * 8);
    acc = __builtin_amdgcn_mfma_f32_16x16x32_bf16(a, b, acc, 0, 0, 0);
  }
  int kout = nt * 16 + r;
#pragma unroll
  for (int i = 0; i < 4; ++i) {
    int jrow = q * 4 + i;
    dst[(((size_t)mt * 128 + (kout >> 3)) << 7) + jrow * 8 + (kout & 7)] = f2bf(acc[i]);
  }
}

// ---------------- persistent RNN kernel ----------------
// Round-19: r10's batch-split RETRY without the VGPR cap.
// r10 post-mortem: __launch_bounds__(512,2) + waves_per_eu(2,2) PROMISE >=2
// waves/EU, i.e. HARD-CAP 128 VGPRs. Batch-split needs 160 VGPR of weights
// alone -> forced spill (VGPR_Count==128 exactly, +430us). The 2nd
// launch_bounds arg is a max-register-budget, not an occupancy hint.
// Fix: __launch_bounds__(512) only. 256 VGPR/thread => 8 waves/CU = exactly
// our 1 block/CU, so an allocator running to ~230 VGPRs costs nothing.
// Canary: VGPR_Count==128 again => allocator still capped, abandon split.
// Everything else identical to r10 (bit-identical output vs r8 proven).

__device__ __forceinline__ void poll3(const unsigned* p, unsigned tgt) {
  unsigned s0, s1, s2;
  asm volatile(
      "s_waitcnt vmcnt(0)\n\t"
      "global_load_dword %0, %3, off sc1\n\t"
      "global_load_dword %1, %3, off sc1\n\t"
      "global_load_dword %2, %3, off sc1\n\t"
      "WL_%=:\n\t"
      "s_waitcnt vmcnt(2)\n\t"
      "v_cmp_lt_u32 vcc, %0, %4\n\t"
      "s_cbranch_vccz WD_%=\n\t"
      "global_load_dword %0, %3, off sc1\n\t"
      "s_waitcnt vmcnt(2)\n\t"
      "v_cmp_lt_u32 vcc, %1, %4\n\t"
      "s_cbranch_vccz WD_%=\n\t"
      "global_load_dword %1, %3, off sc1\n\t"
      "s_waitcnt vmcnt(2)\n\t"
      "v_cmp_lt_u32 vcc, %2, %4\n\t"
      "s_cbranch_vccz WD_%=\n\t"
      "global_load_dword %2, %3, off sc1\n\t"
      "s_branch WL_%=\n\t"
      "WD_%=:\n\t"
      "s_waitcnt vmcnt(0)\n\t"
      : "=&v"(s0), "=&v"(s1), "=&v"(s2)
      : "v"(p), "v"(tgt)
      : "vcc", "memory");
}

// prime wait: 128 own-half producers, block-wide
__device__ __forceinline__ void wait_half(unsigned* F, unsigned tgt, int bh) {
  if (threadIdx.x < 128) poll3(F + bh * 128 + threadIdx.x, tgt);
  __syncthreads();
}

// gen wait: wave's 16 producer octets (ks in {w,w+8,w+16,w+24} x q 0..3)
__device__ __forceinline__ void wait_wave16(unsigned* F, unsigned tgt, int bh) {
  int w = threadIdx.x >> 6, lane = threadIdx.x & 63;
  if (lane < 16) {
    unsigned p = (unsigned)(bh * 128) + 4u * (unsigned)w + 32u * ((unsigned)lane >> 2) + ((unsigned)lane & 3u);
    poll3(F + p, tgt);
  }
}

#define MFMA(a, b, c) __builtin_amdgcn_mfma_f32_16x16x32_bf16((a), (b), (c), 0, 0, 0)

// one 16-batch A-frag per ks, two j-tile B-frags -> two N-tile accs.
// load + consume immediately (no held fragments across waits).
__device__ __forceinline__ void seg_mmN(f32x4& a0, f32x4& a1,
                                        const u16* __restrict__ x,   // pre-offset by bh*128
                                        const short8 (&wa)[4], const short8 (&wb)[4],
                                        int w, int q, int r) {
#pragma unroll
  for (int i = 0; i < 4; ++i) {
    const u16* xp = x + (w + 8 * i) * 1024 + q * 256 + r * 8;
    short8 t0 = *(const short8*)(xp);
    a0 = MFMA(t0, wa[i], a0);
    a1 = MFMA(t0, wb[i], a1);
  }
}

template<int LBASE, int USEGB>
__device__ __forceinline__ void gen_phase(
    f32x4& acc0, f32x4& acc1,                 // pre-seeded with this layer's segB
    const u16* __restrict__ xa,               // segA slot, pre-offset by bh*128
    const short8 (&wAa)[4], const short8 (&wAb)[4],
    const u16* __restrict__ gb,               // Mcomb tile-pair base (USEGB)
    unsigned* waitF, unsigned wtgt,
    const float* __restrict__ bsum, float& creg, u16* __restrict__ hout,
    unsigned* arrF, unsigned aval,
    float (*red)[2][256], int nt)
{
  int tid = threadIdx.x;
  int w = tid >> 6, l = tid & 63, q = l >> 4, r = l & 15;
  int bh = nt >> 7, dt = nt & 127;

  wait_wave16(waitF, wtgt, bh);   // per-wave, 16 producers, no block barrier

  // segA: cross-layer input (fresh)
#pragma unroll
  for (int i = 0; i < 4; ++i) {
    int ks = w + 8 * i;
    const u16* xp = xa + ks * 1024 + q * 256 + r * 8;
    short8 a0 = *(const short8*)(xp);
    short8 ba, bb;
    if constexpr (USEGB) {
      ba = *(const short8*)(gb + (size_t)ks * 512 + l * 8);
      bb = *(const short8*)(gb + 16384 + (size_t)ks * 512 + l * 8);
    } else {
      ba = wAa[i];
      bb = wAb[i];
    }
    acc0 = MFMA(a0, ba, acc0);
    acc1 = MFMA(a0, bb, acc1);
  }

  // epilogue: dump -> barrier -> reduce + direct agent stores + per-wave drain
  *(f32x4*)&red[w][0][l * 4] = acc0;
  *(f32x4*)&red[w][1][l * 4] = acc1;
  __syncthreads();

  if (tid >= LBASE && tid < LBASE + 128) {
    int idx = tid - LBASE;
    int b = idx >> 3, hi = idx & 7, tl = hi >> 2, hl = hi & 3;
    int j0 = dt * 8 + hi;
    float g4[4];
#pragma unroll
    for (int g = 0; g < 4; ++g) {
      int col = g * 4 + hl;
      int lidx = ((b >> 2) * 16 + col) * 4 + (b & 3);
      float s = bsum[g * 1024 + j0];
#pragma unroll
      for (int ww = 0; ww < 8; ++ww) s += red[ww][tl][lidx];
      g4[g] = s;
    }
    float iv = sigm(g4[0]), fv = sigm(g4[1]), gv = tanh_(g4[2]), ov = sigm(g4[3]);
    float cn = fv * creg + iv * gv;
    creg = cn;
    unsigned hv = (unsigned)f2bf(ov * tanh_(cn));
    unsigned other = __shfl_xor(hv, 1);       // partner hi^1 (same b, adjacent lane)
    if ((hi & 1) == 0) {
      unsigned packed = (hv & 0xffffu) | (other << 16);
      size_t doff = (size_t)(dt >> 2) * 1024 + (size_t)(dt & 3) * 256 + (size_t)bh * 128
                  + (size_t)b * 8 + hi;
      __hip_atomic_store((unsigned*)(hout + doff), packed,
                         __ATOMIC_RELAXED, __HIP_MEMORY_SCOPE_AGENT);
    }
    asm volatile("s_waitcnt vmcnt(0)" ::: "memory");   // per-wave drain pre-barrier
  }
  __syncthreads();   // both epilogue waves drained past this point

  if (tid == LBASE)
    __hip_atomic_store(arrF + nt, aval, __ATOMIC_RELAXED, __HIP_MEMORY_SCOPE_AGENT);
}

__global__ __launch_bounds__(512)
void k_rnn(unsigned char* blob) {
  __shared__ float red3[3][8][2][256];   // 48 KB (gen uses slice [0])
  __shared__ u64 hstage[96];             // prime epilogue staging (3 layers x 32 u64)
  const u16* XPRIM = (const u16*)(blob + OFF_XPRIM);
  const u16* tWIH1 = (const u16*)(blob + OFF_WIH1);
  const u16* tMCOMB = (const u16*)(blob + OFF_MCOMB);
  const u16* tWHH1 = (const u16*)(blob + OFF_WHH1);
  const u16* tWIH2 = (const u16*)(blob + OFF_WIH2);
  const u16* tWHH2 = (const u16*)(blob + OFF_WHH2);
  const u16* tWIH3 = (const u16*)(blob + OFF_WIH3);
  const u16* tWHH3 = (const u16*)(blob + OFF_WHH3);
  const float* BS1 = (const float*)(blob + OFF_BS1);
  const float* BS1G = (const float*)(blob + OFF_BS1G);
  const float* BS2 = (const float*)(blob + OFF_BS2);
  const float* BS3 = (const float*)(blob + OFF_BS3);
  u16* H0R = (u16*)(blob + OFF_H0R);
  u16* H1R = (u16*)(blob + OFF_H1R);
  u16* H2R = (u16*)(blob + OFF_H2R);
  u16* H2HIST = (u16*)(blob + OFF_H2HIST);
  const u16* ZEROH = (const u16*)(blob + OFF_ZEROH);
  unsigned* FLAGS = (unsigned*)(blob + OFF_FLAGS);
  unsigned *FP = FLAGS, *F1 = FLAGS + 256, *F2 = FLAGS + 512, *F3 = FLAGS + 768;

  int nt = blockIdx.x;
  int bh = nt >> 7, dt = nt & 127;
  int tid = threadIdx.x;
  int w = tid >> 6, l = tid & 63, q = l >> 4, r = l & 15;
  int layer = tid >> 7, idx = tid & 127;
  const float* BSP = (layer == 0) ? BS1 : (layer == 1) ? BS2 : BS3;
  float creg = 0.f;   // c-state for this thread's (layer, b, hi)

  // ---- prologue: recurrent weight B-fragments (2 j-tiles each) into registers ----
  short8 rWhh1a[4], rWhh1b[4], rWih2a[4], rWih2b[4], rWhh2a[4], rWhh2b[4];
  short8 rWih3a[4], rWih3b[4], rWhh3a[4], rWhh3b[4];
#pragma unroll
  for (int i = 0; i < 4; ++i) {
    size_t offA = (size_t)(2 * dt) * 16384 + (size_t)(w + 8 * i) * 512 + (size_t)l * 8;
    size_t offB = offA + 16384;
    rWhh1a[i] = *(const short8*)(tWHH1 + offA);  rWhh1b[i] = *(const short8*)(tWHH1 + offB);
    rWih2a[i] = *(const short8*)(tWIH2 + offA);  rWih2b[i] = *(const short8*)(tWIH2 + offB);
    rWhh2a[i] = *(const short8*)(tWHH2 + offA);  rWhh2b[i] = *(const short8*)(tWHH2 + offB);
    rWih3a[i] = *(const short8*)(tWIH3 + offA);  rWih3b[i] = *(const short8*)(tWIH3 + offB);
    rWhh3a[i] = *(const short8*)(tWHH3 + offA);  rWhh3b[i] = *(const short8*)(tWHH3 + offB);
  }
  short8 rWih1a = {}, rWih1b = {};
  if (w < 5) {
    size_t o1 = (size_t)(2 * dt) * 2560 + (size_t)w * 512 + (size_t)l * 8;
    rWih1a = *(const short8*)(tWIH1 + o1);
    rWih1b = *(const short8*)(tWIH1 + o1 + 2560);
  }

  // ---- priming phase: 66 pipelined beats (own half only) ----
  // beat b: L1@t=b (b<=63), L2@t=b-1 (1<=b<=64), L3@t=b-2 (2<=b<=65)
  for (int b = 0; b < 66; ++b) {
    f32x4 a10 = {}, a11 = {}, a20 = {}, a21 = {}, a30 = {}, a31 = {};

    // L1 segA (static XPRIM) — before the wait
    if (b < 64 && w < 5) {
      const u16* xp = XPRIM + b * 5120 + w * 1024 + q * 256 + bh * 128 + r * 8;
      short8 x0 = *(const short8*)(xp);
      a10 = MFMA(x0, rWih1a, a10);
      a11 = MFMA(x0, rWih1b, a11);
    }

    wait_half(FP, (unsigned)b, bh);

    // h0_{b-1}: L1 segB (Whh1) + L2 segA (Wih2) — shared fragment loads
    if (b <= 64) {
      const u16* h0p = ((b == 0) ? ZEROH : H0R + (size_t)(b - 1) * 32768) + bh * 128;
#pragma unroll
      for (int i = 0; i < 4; ++i) {
        const u16* xp = h0p + (w + 8 * i) * 1024 + q * 256 + r * 8;
        short8 x0_ = *(const short8*)(xp);
        if (b <= 63) { a10 = MFMA(x0_, rWhh1a[i], a10); a11 = MFMA(x0_, rWhh1b[i], a11); }
        if (b >= 1)  { a20 = MFMA(x0_, rWih2a[i], a20); a21 = MFMA(x0_, rWih2b[i], a21); }
      }
    }
    // h1_{b-2}: L2 segB (Whh2) + L3 segA (Wih3)
    if (b >= 1) {
      const u16* h1p = ((b == 1) ? ZEROH : H1R + (size_t)(b - 2) * 32768) + bh * 128;
#pragma unroll
      for (int i = 0; i < 4; ++i) {
        const u16* xp = h1p + (w + 8 * i) * 1024 + q * 256 + r * 8;
        short8 x0_ = *(const short8*)(xp);
        if (b <= 64) { a20 = MFMA(x0_, rWhh2a[i], a20); a21 = MFMA(x0_, rWhh2b[i], a21); }
        if (b >= 2)  { a30 = MFMA(x0_, rWih3a[i], a30); a31 = MFMA(x0_, rWih3b[i], a31); }
      }
    }
    // h2_{b-3}: L3 segB (Whh3)
    if (b >= 2) {
      const u16* h2p = ((b == 2) ? ZEROH : H2R + (size_t)(b - 3) * 32768) + bh * 128;
#pragma unroll
      for (int i = 0; i < 4; ++i) {
        const u16* xp = h2p + (w + 8 * i) * 1024 + q * 256 + r * 8;
        short8 x0_ = *(const short8*)(xp);
        a30 = MFMA(x0_, rWhh3a[i], a30);
        a31 = MFMA(x0_, rWhh3b[i], a31);
      }
    }

    // fused epilogue: dump all three layers, one barrier, 384-thread reduce
    *(f32x4*)&red3[0][w][0][l * 4] = a10;  *(f32x4*)&red3[0][w][1][l * 4] = a11;
    *(f32x4*)&red3[1][w][0][l * 4] = a20;  *(f32x4*)&red3[1][w][1][l * 4] = a21;
    *(f32x4*)&red3[2][w][0][l * 4] = a30;  *(f32x4*)&red3[2][w][1][l * 4] = a31;
    __syncthreads();

    int tb = b - layer;
    if (tid < 384 && tb >= 0 && tb <= 63) {
      int bb = idx >> 3, hi = idx & 7, tl = hi >> 2, hl = hi & 3;
      int j0 = dt * 8 + hi;
      float g4[4];
#pragma unroll
      for (int g = 0; g < 4; ++g) {
        int col = g * 4 + hl;
        int lidx = ((bb >> 2) * 16 + col) * 4 + (bb & 3);
        float s = BSP[g * 1024 + j0];
#pragma unroll
        for (int ww = 0; ww < 8; ++ww) s += red3[layer][ww][tl][lidx];
        g4[g] = s;
      }
      float iv = sigm(g4[0]), fv = sigm(g4[1]), gv = tanh_(g4[2]), ov = sigm(g4[3]);
      float cn = fv * creg + iv * gv;
      creg = cn;
      ((u16*)hstage)[tid] = f2bf(ov * tanh_(cn));
    }
    __syncthreads();

    // wave 0: 3 conditional u64 slot stores per thread, one drain, one flag
    if (tid < 64) {
      if (tid < 32) {
        int bb2 = tid >> 1, hf = tid & 1;
        size_t doff = (size_t)(dt >> 2) * 1024 + (size_t)(dt & 3) * 256 + (size_t)bh * 128
                    + (size_t)bb2 * 8 + (size_t)hf * 4;
        if (b <= 63)
          __hip_atomic_store((u64*)(H0R + (size_t)b * 32768 + doff), hstage[tid],
                             __ATOMIC_RELAXED, __HIP_MEMORY_SCOPE_AGENT);
        if (b >= 1 && b <= 64)
          __hip_atomic_store((u64*)(H1R + (size_t)(b - 1) * 32768 + doff), hstage[32 + tid],
                             __ATOMIC_RELAXED, __HIP_MEMORY_SCOPE_AGENT);
        if (b >= 2) {
          u16* dst = (b < 65) ? (H2R + (size_t)(b - 2) * 32768) : H2HIST;
          __hip_atomic_store((u64*)(dst + doff), hstage[64 + tid],
                             __ATOMIC_RELAXED, __HIP_MEMORY_SCOPE_AGENT);
        }
      }
      asm volatile("s_waitcnt vmcnt(0)" ::: "memory");
      if (tid == 0)
        __hip_atomic_store(FP + nt, (unsigned)(b + 1), __ATOMIC_RELAXED, __HIP_MEMORY_SCOPE_AGENT);
    }
  }

  // ---- generation phase ----
  // Flag protocol identical to r8; per-wave waits cover the wave's 16
  // producer octets. Visibility proofs unchanged (same-wave prior waits).
  const u16* gbM = tMCOMB + (size_t)(2 * dt) * 16384;   // L2-resident B-frags for L1
  f32x4 c10, c11, c20, c21, c30, c31;

  c10 = {}; c11 = {};
  seg_mmN(c10, c11, H0R + (size_t)63 * 32768 + bh * 128, rWhh1a, rWhh1b, w, q, r);

  for (int t = 64; t < 192; ++t) {
    c20 = {}; c21 = {};
    seg_mmN(c20, c21, H1R + (size_t)(t - 1) * 32768 + bh * 128, rWhh2a, rWhh2b, w, q, r);

    gen_phase<0, 1>(c10, c11, H2HIST + (size_t)(t - 64) * 32768 + bh * 128,
                    rWhh1a, rWhh1b, gbM,
                    (t == 64) ? FP : F3, (t == 64) ? 66u : (unsigned)(t - 64),
                    BS1G, creg, H0R + (size_t)t * 32768,
                    F1, (unsigned)(t - 63), red3[0], nt);

    c30 = {}; c31 = {};
    seg_mmN(c30, c31, H2HIST + (size_t)(t - 64) * 32768 + bh * 128, rWhh3a, rWhh3b, w, q, r);

    gen_phase<128, 0>(c20, c21, H0R + (size_t)t * 32768 + bh * 128,
                      rWih2a, rWih2b, nullptr,
                      F1, (unsigned)(t - 63),
                      BS2, creg, H1R + (size_t)t * 32768,
                      F2, (unsigned)(t - 63), red3[0], nt);

    c10 = {}; c11 = {};
    if (t < 191)
      seg_mmN(c10, c11, H0R + (size_t)t * 32768 + bh * 128, rWhh1a, rWhh1b, w, q, r);

    gen_phase<256, 0>(c30, c31, H1R + (size_t)t * 32768 + bh * 128,
                      rWih3a, rWih3b, nullptr,
                      F2, (unsigned)(t - 63),
                      BS3, creg, H2HIST + (size_t)(t - 63) * 32768,
                      F3, (unsigned)(t - 63), red3[0], nt);
  }
}

// ---------------- batched decoder over all 128 generated h2 states ----------------
__global__ __launch_bounds__(256) void k_dec(const u16* __restrict__ h2hist, const u16* __restrict__ Wd,
                                             const float* __restrict__ bdec, float* __restrict__ out) {
  int blk = blockIdx.x;
  int s = blk / 10, nt = blk - s * 10;
  const u16* x = h2hist + (size_t)(s + 1) * 32768;
  int w = threadIdx.x >> 6, l = threadIdx.x & 63, q = l >> 4, r = l & 15;
  f32x4 acc[2] = {};
  for (int ks = w; ks < 32; ks += 4) {
    const u16* xp = x + ks * 1024 + q * 256 + r * 8;
    short8 a0 = *(const short8*)(xp);
    short8 a1 = *(const short8*)(xp + 128);
    short8 bf = *(const short8*)(Wd + (((size_t)nt * 128 + ks * 4) << 7) + l * 8);
    acc[0] = __builtin_amdgcn_mfma_f32_16x16x32_bf16(a0, bf, acc[0], 0, 0, 0);
    acc[1] = __builtin_amdgcn_mfma_f32_16x16x32_bf16(a1, bf, acc[1], 0, 0, 0);
  }
  __shared__ float red[4][2][256];
#pragma unroll
  for (int mt = 0; mt < 2; ++mt)
#pragma unroll
    for (int i = 0; i < 4; ++i) red[w][mt][l * 4 + i] = acc[mt][i];
  __syncthreads();
  for (int pp = threadIdx.x; pp < 512; pp += 256) {
    int b = pp >> 4, fs = pp & 15;
    int mt = b >> 4, row = b & 15;
    int lidx = ((row >> 2) * 16 + fs) * 4 + (row & 3);
    int f = nt * 16 + fs;
    if (f < 132) {
      float v = red[0][mt][lidx] + red[1][mt][lidx] + red[2][mt][lidx] + red[3][mt][lidx] + bdec[f];
      out[(size_t)b * (128 * 132) + s * 132 + f] = v;
    }
  }
}

// ---------------- host ----------------
extern "C" void kernel_launch(void* const* d_in, const int* in_sizes, int n_in,
                              void* d_out, int out_size, void* d_ws, size_t ws_size,
                              hipStream_t stream) {
  unsigned char* blob = nullptr;
  hipGetSymbolAddress((void**)&blob, HIP_SYMBOL(g_blob));

  const float* iseq = (const float*)d_in[0];
  const float* Wih1 = (const float*)d_in[2];
  const float* Whh1 = (const float*)d_in[3];
  const float* bih1 = (const float*)d_in[4];
  const float* bhh1 = (const float*)d_in[5];
  const float* Wih2 = (const float*)d_in[6];
  const float* Whh2 = (const float*)d_in[7];
  const float* bih2 = (const float*)d_in[8];
  const float* bhh2 = (const float*)d_in[9];
  const float* Wih3 = (const float*)d_in[10];
  const float* Whh3 = (const float*)d_in[11];
  const float* bih3 = (const float*)d_in[12];
  const float* bhh3 = (const float*)d_in[13];
  const float* Wdec = (const float*)d_in[14];
  const float* bdec = (const float*)d_in[15];

  u16* tWIH1 = (u16*)(blob + OFF_WIH1);
  u16* tWDECF = (u16*)(blob + OFF_WDECF);
  u16* tWDECB = (u16*)(blob + OFF_WDECB);
  u16* tMCOMB = (u16*)(blob + OFF_MCOMB);
  u16* H2HIST = (u16*)(blob + OFF_H2HIST);

  // fused prep: 3 launches
  k_prep1<<<2560, 256, 0, stream>>>(Whh1, Wih2, Whh2, Wih3, Whh3, blob);
  k_prep2<<<496, 256, 0, stream>>>(Wih1, Wdec, iseq, bih1, bhh1, bih2, bhh2, bih3, bhh3, bdec, blob);
  k_mcomb<<<4096, 256, 0, stream>>>(tWIH1, tWDECB, tMCOMB);

  // persistent RNN
  {
    void* args[] = { (void*)&blob };
    hipError_t ce = hipLaunchCooperativeKernel((void*)k_rnn, dim3(256), dim3(512), args, 0, stream);
    if (ce != hipSuccess) {
      k_rnn<<<dim3(256), dim3(512), 0, stream>>>(blob);
    }
  }

  // batched decoder -> d_out fp32 [32][128][132]
  k_dec<<<1280, 256, 0, stream>>>(H2HIST, tWDECF, bdec, (float*)d_out);
}

// Round 12
// 2172.114 us; speedup vs baseline: 1.2254x; 1.2254x over previous
//
#include <hip/hip_runtime.h>
#include <stdint.h>

typedef unsigned short u16;
typedef unsigned long long u64;
typedef __attribute__((ext_vector_type(8))) short short8;
typedef __attribute__((ext_vector_type(4))) float f32x4;

// ---------------- device-global blob ----------------
#define SZ_BIGW    (4096ull*1024ull*2ull)          // [4096x1024] bf16, fragment-tiled
#define OFF_WHH1   (0ull)
#define OFF_WIH2   (OFF_WHH1 + SZ_BIGW)
#define OFF_WHH2   (OFF_WIH2 + SZ_BIGW)
#define OFF_WIH3   (OFF_WHH2 + SZ_BIGW)
#define OFF_WHH3   (OFF_WIH3 + SZ_BIGW)
#define OFF_MCOMB  (OFF_WHH3 + SZ_BIGW)            // W_ih1 @ W_dec  [4096x1024]
#define OFF_WIH1   (OFF_MCOMB + SZ_BIGW)           // [4096 x 160(pad of 132)]
#define SZ_WIH1    (4096ull*160ull*2ull)
#define OFF_WDECF  (OFF_WIH1 + SZ_WIH1)            // W_dec as B-op, rows f(pad160) x K=1024
#define SZ_WDECF   (160ull*1024ull*2ull)
#define OFF_WDECB  (OFF_WDECF + SZ_WDECF)          // W_dec^T as B-op, rows k(1024) x f(pad160)
#define SZ_WDECB   (1024ull*160ull*2ull)
#define OFF_XPRIM  (OFF_WDECB + SZ_WDECB)          // [64 t][20 kc][32 b][8] bf16
#define SZ_XPRIM   (64ull*5120ull*2ull)
#define OFF_H2HIST (OFF_XPRIM + SZ_XPRIM)          // 129 slots (A-layout), slot0 = prime t=63
#define SZ_HSLOT   (32768ull*2ull)                 // 64 KB per h slot
#define SZ_H2HIST  (129ull*SZ_HSLOT)
#define OFF_H0R    (OFF_H2HIST + SZ_H2HIST)        // write-once ring, depth 192
#define SZ_HR      (192ull*SZ_HSLOT)
#define OFF_H1R    (OFF_H0R + SZ_HR)
#define OFF_H2R    (OFF_H1R + SZ_HR)               // prime-phase ring, depth 64
#define SZ_H2R     (64ull*SZ_HSLOT)
#define OFF_ZEROH  (OFF_H2R + SZ_H2R)              // one zero h slot
#define OFF_FLAGS  (OFF_ZEROH + SZ_HSLOT)          // 4 x 256 u32 flags (FP,F1,F2,F3)
#define SZ_FLAGS   (4096ull)
#define OFF_BS1    (OFF_FLAGS + SZ_FLAGS)          // bias sums fp32 [4096] x4
#define OFF_BS1G   (OFF_BS1 + 16384ull)
#define OFF_BS2    (OFF_BS1G + 16384ull)
#define OFF_BS3    (OFF_BS2 + 16384ull)
#define BLOB_SIZE  (OFF_BS3 + 16384ull)

__device__ unsigned char g_blob[BLOB_SIZE];

// zero region: ZEROH + FLAGS, contiguous
#define ZERO_BYTES (SZ_HSLOT + SZ_FLAGS)

__device__ __forceinline__ u16 f2bf(float f) {
  unsigned u = __float_as_uint(f);
  u += 0x7fffu + ((u >> 16) & 1u);
  return (u16)(u >> 16);
}
__device__ __forceinline__ float sigm(float x) { return 1.f / (1.f + __expf(-x)); }
__device__ __forceinline__ float tanh_(float x) {
  x = fminf(fmaxf(x, -40.f), 40.f);
  float e = __expf(2.f * x);
  return (e - 1.f) / (e + 1.f);
}

// ---------------- fused prep kernels ----------------
__device__ __forceinline__ void dev_swizzle(const float* __restrict__ src, u16* __restrict__ dst,
                                            int J, int Jsrc, int Kpad, int Ksrc, int srcld,
                                            int transposed, int perm, int bbase, int nblocks) {
  int total = J * Kpad;
  int nkc = Kpad >> 3;
  for (int o = (blockIdx.x - bbase) * 256 + threadIdx.x; o < total; o += nblocks * 256) {
    int chunk = o >> 7, within = o & 127;
    int nt = chunk / nkc, kc = chunk - nt * nkc;
    int jr = within >> 3, ke = within & 7;
    int j = perm ? ((jr >> 2) * 1024 + nt * 4 + (jr & 3)) : (nt * 16 + jr);
    int k = kc * 8 + ke;
    float v = 0.f;
    if (j < Jsrc && k < Ksrc)
      v = transposed ? src[(size_t)k * srcld + j] : src[(size_t)j * srcld + k];
    dst[o] = f2bf(v);
  }
}

// 5 big [4096x1024] perm=1 swizzles; 512 blocks per matrix, dsts contiguous in blob.
__global__ __launch_bounds__(256) void k_prep1(const float* __restrict__ s0, const float* __restrict__ s1,
                                               const float* __restrict__ s2, const float* __restrict__ s3,
                                               const float* __restrict__ s4, unsigned char* blob) {
  int m = blockIdx.x >> 9;
  const float* src = (m == 0) ? s0 : (m == 1) ? s1 : (m == 2) ? s2 : (m == 3) ? s3 : s4;
  u16* dst = (u16*)(blob + (size_t)m * SZ_BIGW);
  int nkc = 128;   // Kpad=1024
  for (int o = (blockIdx.x & 511) * 256 + threadIdx.x; o < 4096 * 1024; o += 512 * 256) {
    int chunk = o >> 7, within = o & 127;
    int nt = chunk / nkc, kc = chunk - nt * nkc;
    int jr = within >> 3, ke = within & 7;
    int j = (jr >> 2) * 1024 + nt * 4 + (jr & 3);
    int k = kc * 8 + ke;
    dst[o] = f2bf(src[(size_t)j * 1024 + k]);
  }
}

// everything small, block-range partitioned: [0,64) zero; [64,320) WIH1;
// [320,352) WDECF; [352,384) WDECB; [384,480) XPRIM; [480,496) bias.
__global__ __launch_bounds__(256) void k_prep2(const float* __restrict__ Wih1, const float* __restrict__ Wdec,
                                               const float* __restrict__ iseq,
                                               const float* bih1, const float* bhh1,
                                               const float* bih2, const float* bhh2,
                                               const float* bih3, const float* bhh3,
                                               const float* __restrict__ bdec, unsigned char* blob) {
  int bid = blockIdx.x;
  if (bid < 64) {
    uint4* p = (uint4*)(blob + OFF_ZEROH);
    int i = bid * 256 + threadIdx.x;
    if (i < (int)(ZERO_BYTES / 16)) p[i] = make_uint4(0u, 0u, 0u, 0u);
  } else if (bid < 320) {
    dev_swizzle(Wih1, (u16*)(blob + OFF_WIH1), 4096, 4096, 160, 132, 132, 0, 1, 64, 256);
  } else if (bid < 352) {
    dev_swizzle(Wdec, (u16*)(blob + OFF_WDECF), 160, 132, 1024, 1024, 1024, 0, 0, 320, 32);
  } else if (bid < 384) {
    dev_swizzle(Wdec, (u16*)(blob + OFF_WDECB), 1024, 1024, 160, 132, 1024, 1, 0, 352, 32);
  } else if (bid < 480) {
    u16* dst = (u16*)(blob + OFF_XPRIM);
    for (int o = (bid - 384) * 256 + threadIdx.x; o < 64 * 5120; o += 96 * 256) {
      int t = o / 5120, rem = o - t * 5120;
      int kc = rem >> 8, b = (rem >> 3) & 31, ke = rem & 7;
      int k = kc * 8 + ke;
      float v = (k < 132) ? iseq[(size_t)b * (64 * 132) + t * 132 + k] : 0.f;
      dst[o] = f2bf(v);
    }
  } else {
    int j = (bid - 480) * 256 + threadIdx.x;
    if (j < 4096) {
      float* bs1 = (float*)(blob + OFF_BS1);
      float* bs1g = (float*)(blob + OFF_BS1G);
      float* bs2 = (float*)(blob + OFF_BS2);
      float* bs3 = (float*)(blob + OFF_BS3);
      float s1 = bih1[j] + bhh1[j];
      float bc = 0.f;
      const float* wr = Wih1 + (size_t)j * 132;
      for (int f = 0; f < 132; ++f) bc += wr[f] * bdec[f];
      bs1[j] = s1;
      bs1g[j] = s1 + bc;
      bs2[j] = bih2[j] + bhh2[j];
      bs3[j] = bih3[j] + bhh3[j];
    }
  }
}

// Mcomb[j][k] = sum_f Wih1[j][f]*Wdec[f][k]; A-rows and C-rows permute identically.
__global__ __launch_bounds__(256) void k_mcomb(const u16* __restrict__ A, const u16* __restrict__ Bm,
                                               u16* __restrict__ dst) {
  int blk = blockIdx.x;                   // 4096 = 256 mt x 16 jg
  int mt = blk & 255, jg = blk >> 8;
  int w = threadIdx.x >> 6, l = threadIdx.x & 63, q = l >> 4, r = l & 15;
  int nt = jg * 4 + w;
  f32x4 acc = {};
  for (int ks = 0; ks < 5; ++ks) {
    short8 a = *(const short8*)(A + ((size_t)mt * 20 + ks * 4 + q) * 128 + r * 8);
    short8 b = *(const short8*)(Bm + ((size_t)nt * 20 + ks * 4 + q) * 128 + r * 8);
    acc = __builtin_amdgcn_mfma_f32_16x16x32_bf16(a, b, acc, 0, 0, 0);
  }
  int kout = nt * 16 + r;
#pragma unroll
  for (int i = 0; i < 4; ++i) {
    int jrow = q * 4 + i;
    dst[(((size_t)mt * 128 + (kout >> 3)) << 7) + jrow * 8 + (kout & 7)] = f2bf(acc[i]);
  }
}

// ---------------- persistent RNN kernel (r9/r8 proven-best state) ----------------
// Round-20: REVERT to r9 (best verified: k_rnn ~2005-2016us, total 2230us).
// Post-mortem ledger: the per-hop ~4.45us survived 8 attacks (poll depth,
// poll scope, per-wave waits, counter protocol, segB pre-seed, direct stores,
// prep fusion, batch-split x2 — both spill-confounded: allocator heuristic
// caps at 128 VGPR regardless of launch_bounds form). This is an
// algorithmic-latency floor: 450 serial chip-wide dependency hops
// (autoregressive 3-layer chain L3(t-1)->L1(t)->L2(t)->L3(t)), each ~3
// agent-scope LLC round-trips + producer-max jitter. HBM 1.7% / MFMA 6%
// confirm neither classical roofline applies.

__device__ __forceinline__ void poll3(const unsigned* p, unsigned tgt) {
  unsigned s0, s1, s2;
  asm volatile(
      "s_waitcnt vmcnt(0)\n\t"
      "global_load_dword %0, %3, off sc1\n\t"
      "global_load_dword %1, %3, off sc1\n\t"
      "global_load_dword %2, %3, off sc1\n\t"
      "WL_%=:\n\t"
      "s_waitcnt vmcnt(2)\n\t"
      "v_cmp_lt_u32 vcc, %0, %4\n\t"
      "s_cbranch_vccz WD_%=\n\t"
      "global_load_dword %0, %3, off sc1\n\t"
      "s_waitcnt vmcnt(2)\n\t"
      "v_cmp_lt_u32 vcc, %1, %4\n\t"
      "s_cbranch_vccz WD_%=\n\t"
      "global_load_dword %1, %3, off sc1\n\t"
      "s_waitcnt vmcnt(2)\n\t"
      "v_cmp_lt_u32 vcc, %2, %4\n\t"
      "s_cbranch_vccz WD_%=\n\t"
      "global_load_dword %2, %3, off sc1\n\t"
      "s_branch WL_%=\n\t"
      "WD_%=:\n\t"
      "s_waitcnt vmcnt(0)\n\t"
      : "=&v"(s0), "=&v"(s1), "=&v"(s2)
      : "v"(p), "v"(tgt)
      : "vcc", "memory");
}

__device__ __forceinline__ void wait_all(unsigned* F, unsigned tgt) {
  if (threadIdx.x < 256) poll3(F + threadIdx.x, tgt);
  __syncthreads();
}

// per-wave wait: lanes 0-31 poll the 32 producers sourcing this wave's rows
__device__ __forceinline__ void wait_wave(unsigned* F, unsigned tgt) {
  int w = threadIdx.x >> 6, lane = threadIdx.x & 63;
  if (lane < 32) {
    unsigned p = 8u * (unsigned)w + 64u * ((unsigned)lane >> 3) + ((unsigned)lane & 7u);
    poll3(F + p, tgt);
  }
}

#define MFMA(a, b, c) __builtin_amdgcn_mfma_f32_16x16x32_bf16((a), (b), (c), 0, 0, 0)

// load 8 A-fragments of one slot and immediately consume into acc (no held state)
__device__ __forceinline__ void seg_mm(f32x4& a0, f32x4& a1,
                                       const u16* __restrict__ x, const short8 (&wt)[4],
                                       int w, int q, int r) {
#pragma unroll
  for (int i = 0; i < 4; ++i) {
    const u16* xp = x + (w + 8 * i) * 1024 + q * 256 + r * 8;
    short8 t0 = *(const short8*)(xp);
    short8 t1 = *(const short8*)(xp + 128);
    a0 = MFMA(t0, wt[i], a0);
    a1 = MFMA(t1, wt[i], a1);
  }
}

template<int LBASE>
__device__ __forceinline__ void gen_phase(
    f32x4& acc0, f32x4& acc1,                 // pre-seeded with this layer's segB
    const u16* __restrict__ xa, const short8 (&wA)[4],
    unsigned* waitF, unsigned wtgt,
    const float* __restrict__ bsum, float& creg, u16* __restrict__ hout,
    unsigned* arrF, unsigned aval,
    float (*red)[2][256], int nt)
{
  int tid = threadIdx.x;
  int w = tid >> 6, l = tid & 63, q = l >> 4, r = l & 15;

  wait_wave(waitF, wtgt);   // per-wave, no block barrier

  // segA: cross-layer input (fresh)
#pragma unroll
  for (int i = 0; i < 4; ++i) {
    const u16* xp = xa + (w + 8 * i) * 1024 + q * 256 + r * 8;
    short8 a0 = *(const short8*)(xp);
    short8 a1 = *(const short8*)(xp + 128);
    acc0 = MFMA(a0, wA[i], acc0);
    acc1 = MFMA(a1, wA[i], acc1);
  }

  // epilogue: dump -> barrier -> reduce + DIRECT agent stores + per-wave drain
  *(f32x4*)&red[w][0][l * 4] = acc0;
  *(f32x4*)&red[w][1][l * 4] = acc1;
  __syncthreads();

  if (tid >= LBASE && tid < LBASE + 128) {
    int idx = tid - LBASE;
    int b = idx >> 2, hl = idx & 3, mt = b >> 4, row = b & 15;
    int j0 = nt * 4 + hl;
    float g4[4];
#pragma unroll
    for (int g = 0; g < 4; ++g) {
      int col = g * 4 + hl;
      int lidx = ((row >> 2) * 16 + col) * 4 + (row & 3);
      float s = bsum[g * 1024 + j0];
#pragma unroll
      for (int ww = 0; ww < 8; ++ww) s += red[ww][mt][lidx];
      g4[g] = s;
    }
    float iv = sigm(g4[0]), fv = sigm(g4[1]), gv = tanh_(g4[2]), ov = sigm(g4[3]);
    float cn = fv * creg + iv * gv;
    creg = cn;
    unsigned hv = (unsigned)f2bf(ov * tanh_(cn));
    unsigned other = __shfl_xor(hv, 1);       // partner hl^1 (same b, same wave)
    if ((hl & 1) == 0) {
      unsigned packed = (hv & 0xffffu) | (other << 16);
      unsigned* dp = (unsigned*)(hout + ((size_t)(nt >> 1) * 256 +
                                         (size_t)b * 8 + (size_t)(nt & 1) * 4 + hl));
      __hip_atomic_store(dp, packed, __ATOMIC_RELAXED, __HIP_MEMORY_SCOPE_AGENT);
    }
    asm volatile("s_waitcnt vmcnt(0)" ::: "memory");   // per-wave drain pre-barrier
  }
  __syncthreads();   // both epilogue waves drained past this point

  if (tid == LBASE)
    __hip_atomic_store(arrF + nt, aval, __ATOMIC_RELAXED, __HIP_MEMORY_SCOPE_AGENT);
}

__global__ __launch_bounds__(512, 2) void k_rnn(unsigned char* blob) {
  __shared__ float red3[3][8][2][256];   // 48 KB (gen uses slice [0])
  __shared__ u64 hstage[96];             // prime epilogue staging (3 layers x 32 u64)
  const u16* XPRIM = (const u16*)(blob + OFF_XPRIM);
  const u16* tWIH1 = (const u16*)(blob + OFF_WIH1);
  const u16* tMCOMB = (const u16*)(blob + OFF_MCOMB);
  const u16* tWHH1 = (const u16*)(blob + OFF_WHH1);
  const u16* tWIH2 = (const u16*)(blob + OFF_WIH2);
  const u16* tWHH2 = (const u16*)(blob + OFF_WHH2);
  const u16* tWIH3 = (const u16*)(blob + OFF_WIH3);
  const u16* tWHH3 = (const u16*)(blob + OFF_WHH3);
  const float* BS1 = (const float*)(blob + OFF_BS1);
  const float* BS1G = (const float*)(blob + OFF_BS1G);
  const float* BS2 = (const float*)(blob + OFF_BS2);
  const float* BS3 = (const float*)(blob + OFF_BS3);
  u16* H0R = (u16*)(blob + OFF_H0R);
  u16* H1R = (u16*)(blob + OFF_H1R);
  u16* H2R = (u16*)(blob + OFF_H2R);
  u16* H2HIST = (u16*)(blob + OFF_H2HIST);
  const u16* ZEROH = (const u16*)(blob + OFF_ZEROH);
  unsigned* FLAGS = (unsigned*)(blob + OFF_FLAGS);
  unsigned *FP = FLAGS, *F1 = FLAGS + 256, *F2 = FLAGS + 512, *F3 = FLAGS + 768;

  int nt = blockIdx.x;
  int tid = threadIdx.x;
  int w = tid >> 6, l = tid & 63, q = l >> 4, r = l & 15;
  int layer = tid >> 7, idx = tid & 127;
  const float* BSP = (layer == 0) ? BS1 : (layer == 1) ? BS2 : BS3;
  float creg = 0.f;   // c-state for this thread's layer (layer = tid>>7)

  // ---- prologue: all weight B-fragments into registers ----
  short8 rWhh1[4], rWih2[4], rWhh2[4], rWih3[4], rWhh3[4];
#pragma unroll
  for (int i = 0; i < 4; ++i) {
    size_t off = (size_t)nt * 16384 + (size_t)(w + 8 * i) * 512 + (size_t)l * 8;
    rWhh1[i] = *(const short8*)(tWHH1 + off);
    rWih2[i] = *(const short8*)(tWIH2 + off);
    rWhh2[i] = *(const short8*)(tWHH2 + off);
    rWih3[i] = *(const short8*)(tWIH3 + off);
    rWhh3[i] = *(const short8*)(tWHH3 + off);
  }
  short8 rWih1 = {};
  if (w < 5)
    rWih1 = *(const short8*)(tWIH1 + (size_t)nt * 2560 + (size_t)w * 512 + (size_t)l * 8);

  // ---- priming phase: 66 pipelined beats ----
  // beat b: L1@t=b (valid b<=63), L2@t=b-1 (1<=b<=64), L3@t=b-2 (2<=b<=65)
  for (int b = 0; b < 66; ++b) {
    f32x4 a10 = {}, a11 = {}, a20 = {}, a21 = {}, a30 = {}, a31 = {};

    // L1 segA (static XPRIM) — before the wait
    if (b < 64 && w < 5) {
      const u16* xp = XPRIM + b * 5120 + w * 1024 + q * 256 + r * 8;
      short8 x0 = *(const short8*)(xp);
      short8 x1 = *(const short8*)(xp + 128);
      a10 = MFMA(x0, rWih1, a10);
      a11 = MFMA(x1, rWih1, a11);
    }

    wait_all(FP, (unsigned)b);

    // h0_{b-1}: L1 segB (Whh1) + L2 segA (Wih2) — shared fragment loads
    if (b <= 64) {
      const u16* h0p = (b == 0) ? ZEROH : H0R + (size_t)(b - 1) * 32768;
#pragma unroll
      for (int i = 0; i < 4; ++i) {
        const u16* xp = h0p + (w + 8 * i) * 1024 + q * 256 + r * 8;
        short8 x0_ = *(const short8*)(xp);
        short8 x1_ = *(const short8*)(xp + 128);
        if (b <= 63) { a10 = MFMA(x0_, rWhh1[i], a10); a11 = MFMA(x1_, rWhh1[i], a11); }
        if (b >= 1)  { a20 = MFMA(x0_, rWih2[i], a20); a21 = MFMA(x1_, rWih2[i], a21); }
      }
    }
    // h1_{b-2}: L2 segB (Whh2) + L3 segA (Wih3)
    if (b >= 1) {
      const u16* h1p = (b == 1) ? ZEROH : H1R + (size_t)(b - 2) * 32768;
#pragma unroll
      for (int i = 0; i < 4; ++i) {
        const u16* xp = h1p + (w + 8 * i) * 1024 + q * 256 + r * 8;
        short8 x0_ = *(const short8*)(xp);
        short8 x1_ = *(const short8*)(xp + 128);
        if (b <= 64) { a20 = MFMA(x0_, rWhh2[i], a20); a21 = MFMA(x1_, rWhh2[i], a21); }
        if (b >= 2)  { a30 = MFMA(x0_, rWih3[i], a30); a31 = MFMA(x1_, rWih3[i], a31); }
      }
    }
    // h2_{b-3}: L3 segB (Whh3)
    if (b >= 2) {
      const u16* h2p = (b == 2) ? ZEROH : H2R + (size_t)(b - 3) * 32768;
#pragma unroll
      for (int i = 0; i < 4; ++i) {
        const u16* xp = h2p + (w + 8 * i) * 1024 + q * 256 + r * 8;
        short8 x0_ = *(const short8*)(xp);
        short8 x1_ = *(const short8*)(xp + 128);
        a30 = MFMA(x0_, rWhh3[i], a30);
        a31 = MFMA(x1_, rWhh3[i], a31);
      }
    }

    // fused epilogue: dump all three layers, one barrier, 384-thread reduce
    *(f32x4*)&red3[0][w][0][l * 4] = a10;  *(f32x4*)&red3[0][w][1][l * 4] = a11;
    *(f32x4*)&red3[1][w][0][l * 4] = a20;  *(f32x4*)&red3[1][w][1][l * 4] = a21;
    *(f32x4*)&red3[2][w][0][l * 4] = a30;  *(f32x4*)&red3[2][w][1][l * 4] = a31;
    __syncthreads();

    int tb = b - layer;
    if (tid < 384 && tb >= 0 && tb <= 63) {
      int bb = idx >> 2, hl = idx & 3, mt = bb >> 4, row = bb & 15;
      int j0 = nt * 4 + hl;
      float g4[4];
#pragma unroll
      for (int g = 0; g < 4; ++g) {
        int col = g * 4 + hl;
        int lidx = ((row >> 2) * 16 + col) * 4 + (row & 3);
        float s = BSP[g * 1024 + j0];
#pragma unroll
        for (int ww = 0; ww < 8; ++ww) s += red3[layer][ww][mt][lidx];
        g4[g] = s;
      }
      float iv = sigm(g4[0]), fv = sigm(g4[1]), gv = tanh_(g4[2]), ov = sigm(g4[3]);
      float cn = fv * creg + iv * gv;
      creg = cn;
      ((u16*)hstage)[tid] = f2bf(ov * tanh_(cn));
    }
    __syncthreads();

    // wave 0: up to 3 slot stores, one drain, one flag
    if (tid < 64) {
      if (tid < 32) {
        size_t doff = (size_t)(nt >> 1) * 256 + (size_t)tid * 8 + (size_t)(nt & 1) * 4;
        if (b <= 63)
          __hip_atomic_store((u64*)(H0R + (size_t)b * 32768 + doff), hstage[tid],
                             __ATOMIC_RELAXED, __HIP_MEMORY_SCOPE_AGENT);
        if (b >= 1 && b <= 64)
          __hip_atomic_store((u64*)(H1R + (size_t)(b - 1) * 32768 + doff), hstage[32 + tid],
                             __ATOMIC_RELAXED, __HIP_MEMORY_SCOPE_AGENT);
        if (b >= 2) {
          u16* dst = (b < 65) ? (H2R + (size_t)(b - 2) * 32768) : H2HIST;
          __hip_atomic_store((u64*)(dst + doff), hstage[64 + tid],
                             __ATOMIC_RELAXED, __HIP_MEMORY_SCOPE_AGENT);
        }
      }
      asm volatile("s_waitcnt vmcnt(0)" ::: "memory");
      if (tid == 0)
        __hip_atomic_store(FP + nt, (unsigned)(b + 1), __ATOMIC_RELAXED, __HIP_MEMORY_SCOPE_AGENT);
    }
  }

  // Mcomb fragments only needed for gen — load after prime to cap VGPR pressure
  short8 rMcomb[4];
#pragma unroll
  for (int i = 0; i < 4; ++i)
    rMcomb[i] = *(const short8*)(tMCOMB + (size_t)nt * 16384 + (size_t)(w + 8 * i) * 512 + (size_t)l * 8);

  // ---- generation phase ----
  // Per step t, three phases; each phase pre-computes the NEXT phase's segB
  // (load + MFMA into a dedicated acc pair, consumed immediately) before its
  // own wait. Visibility proofs (per-wave: every seed reads exactly the rows
  // whose producers the SAME wave's previous-phase wait covered):
  //   L1(64) seed H0R[63]: prime beat 65 waited FP>=65 block-wide.
  //   L2(t) seed H1R[t-1]: t=64 via FP>=65; t>64 via F2>=t-64 @L3(t-1).
  //   L3(t) seed H2HIST[t-64]: t=64 via FP>=66; t>64 via F3>=t-64 @L1(t).
  //   L1(t+1) seed H0R[t]: via F1>=t-63 @L2(t).
  f32x4 c10, c11, c20, c21, c30, c31;

  c10 = {}; c11 = {};
  seg_mm(c10, c11, H0R + (size_t)63 * 32768, rWhh1, w, q, r);

  for (int t = 64; t < 192; ++t) {
    c20 = {}; c21 = {};
    seg_mm(c20, c21, H1R + (size_t)(t - 1) * 32768, rWhh2, w, q, r);

    gen_phase<0>(c10, c11, H2HIST + (size_t)(t - 64) * 32768, rMcomb,
                 (t == 64) ? FP : F3, (t == 64) ? 66u : (unsigned)(t - 64),
                 BS1G, creg, H0R + (size_t)t * 32768,
                 F1, (unsigned)(t - 63), red3[0], nt);

    c30 = {}; c31 = {};
    seg_mm(c30, c31, H2HIST + (size_t)(t - 64) * 32768, rWhh3, w, q, r);

    gen_phase<128>(c20, c21, H0R + (size_t)t * 32768, rWih2,
                   F1, (unsigned)(t - 63),
                   BS2, creg, H1R + (size_t)t * 32768,
                   F2, (unsigned)(t - 63), red3[0], nt);

    c10 = {}; c11 = {};
    if (t < 191)
      seg_mm(c10, c11, H0R + (size_t)t * 32768, rWhh1, w, q, r);

    gen_phase<256>(c30, c31, H1R + (size_t)t * 32768, rWih3,
                   F2, (unsigned)(t - 63),
                   BS3, creg, H2HIST + (size_t)(t - 63) * 32768,
                   F3, (unsigned)(t - 63), red3[0], nt);
  }
}

// ---------------- batched decoder over all 128 generated h2 states ----------------
__global__ __launch_bounds__(256) void k_dec(const u16* __restrict__ h2hist, const u16* __restrict__ Wd,
                                             const float* __restrict__ bdec, float* __restrict__ out) {
  int blk = blockIdx.x;
  int s = blk / 10, nt = blk - s * 10;
  const u16* x = h2hist + (size_t)(s + 1) * 32768;
  int w = threadIdx.x >> 6, l = threadIdx.x & 63, q = l >> 4, r = l & 15;
  f32x4 acc[2] = {};
  for (int ks = w; ks < 32; ks += 4) {
    const u16* xp = x + ks * 1024 + q * 256 + r * 8;
    short8 a0 = *(const short8*)(xp);
    short8 a1 = *(const short8*)(xp + 128);
    short8 bf = *(const short8*)(Wd + (((size_t)nt * 128 + ks * 4) << 7) + l * 8);
    acc[0] = __builtin_amdgcn_mfma_f32_16x16x32_bf16(a0, bf, acc[0], 0, 0, 0);
    acc[1] = __builtin_amdgcn_mfma_f32_16x16x32_bf16(a1, bf, acc[1], 0, 0, 0);
  }
  __shared__ float red[4][2][256];
#pragma unroll
  for (int mt = 0; mt < 2; ++mt)
#pragma unroll
    for (int i = 0; i < 4; ++i) red[w][mt][l * 4 + i] = acc[mt][i];
  __syncthreads();
  for (int pp = threadIdx.x; pp < 512; pp += 256) {
    int b = pp >> 4, fs = pp & 15;
    int mt = b >> 4, row = b & 15;
    int lidx = ((row >> 2) * 16 + fs) * 4 + (row & 3);
    int f = nt * 16 + fs;
    if (f < 132) {
      float v = red[0][mt][lidx] + red[1][mt][lidx] + red[2][mt][lidx] + red[3][mt][lidx] + bdec[f];
      out[(size_t)b * (128 * 132) + s * 132 + f] = v;
    }
  }
}

// ---------------- host ----------------
extern "C" void kernel_launch(void* const* d_in, const int* in_sizes, int n_in,
                              void* d_out, int out_size, void* d_ws, size_t ws_size,
                              hipStream_t stream) {
  unsigned char* blob = nullptr;
  hipGetSymbolAddress((void**)&blob, HIP_SYMBOL(g_blob));

  const float* iseq = (const float*)d_in[0];
  const float* Wih1 = (const float*)d_in[2];
  const float* Whh1 = (const float*)d_in[3];
  const float* bih1 = (const float*)d_in[4];
  const float* bhh1 = (const float*)d_in[5];
  const float* Wih2 = (const float*)d_in[6];
  const float* Whh2 = (const float*)d_in[7];
  const float* bih2 = (const float*)d_in[8];
  const float* bhh2 = (const float*)d_in[9];
  const float* Wih3 = (const float*)d_in[10];
  const float* Whh3 = (const float*)d_in[11];
  const float* bih3 = (const float*)d_in[12];
  const float* bhh3 = (const float*)d_in[13];
  const float* Wdec = (const float*)d_in[14];
  const float* bdec = (const float*)d_in[15];

  u16* tWIH1 = (u16*)(blob + OFF_WIH1);
  u16* tWDECF = (u16*)(blob + OFF_WDECF);
  u16* tWDECB = (u16*)(blob + OFF_WDECB);
  u16* tMCOMB = (u16*)(blob + OFF_MCOMB);
  u16* H2HIST = (u16*)(blob + OFF_H2HIST);

  // fused prep: 3 launches
  k_prep1<<<2560, 256, 0, stream>>>(Whh1, Wih2, Whh2, Wih3, Whh3, blob);
  k_prep2<<<496, 256, 0, stream>>>(Wih1, Wdec, iseq, bih1, bhh1, bih2, bhh2, bih3, bhh3, bdec, blob);
  k_mcomb<<<4096, 256, 0, stream>>>(tWIH1, tWDECB, tMCOMB);

  // persistent RNN
  {
    void* args[] = { (void*)&blob };
    hipError_t ce = hipLaunchCooperativeKernel((void*)k_rnn, dim3(256), dim3(512), args, 0, stream);
    if (ce != hipSuccess) {
      k_rnn<<<dim3(256), dim3(512), 0, stream>>>(blob);
    }
  }

  // batched decoder -> d_out fp32 [32][128][132]
  k_dec<<<1280, 256, 0, stream>>>(H2HIST, tWDECF, bdec, (float*)d_out);
}